// Round 16
// baseline (579.915 us; speedup 1.0000x reference)
//
#include <hip/hip_runtime.h>
#include <hip/hip_cooperative_groups.h>
#include <cstdint>
#include <cstddef>

namespace cg = cooperative_groups;

#define N_NODES 50000
#define N_EDGES 800000
#define NE4 (N_EDGES / 4)        // 200000 int4 records
#define DIM 64
#define NREL 8
#define NBLK 782                 // ceil(N_NODES/64)
#define NPAD (NBLK * 64)         // 50048
#define NBUCK 196                // ceil(N_NODES/256): bucket = dst>>8
#define NCHUNK 196               // edge chunks of 4096
#define CHUNK4 1024              // int4 loads per chunk
#define NP (NBUCK * NCHUNK)      // 38416 count-matrix entries
#define NSCAN 151                // ceil(NP/256) scanA blocks
#define NGRID 978                // max(NCHUNK+NBLK, NBLK+NSCAN) = 978
#define NGRP (N_NODES / 4)       // 12500 fused node-groups

typedef unsigned short u16;
typedef unsigned int u32;
typedef float f32x4 __attribute__((ext_vector_type(4)));
typedef short bf16x8 __attribute__((ext_vector_type(8)));

__device__ __forceinline__ u16 f2b(float f) {
  union { float f; u32 u; } c; c.f = f;
  u32 u = c.u;
  return (u16)((u + 0x7fffu + ((u >> 16) & 1u)) >> 16);  // RNE
}
__device__ __forceinline__ float b2f(u16 v) {
  union { u32 u; float f; } c; c.u = ((u32)v) << 16;
  return c.f;
}

__global__ __launch_bounds__(256) void k_mega(
    const float* __restrict__ h, const float* __restrict__ W,
    const float* __restrict__ a, const float* __restrict__ dmask,
    const int* __restrict__ src, const int* __restrict__ dst,
    const int* __restrict__ et, u16* __restrict__ hb, u16* __restrict__ WbT,
    u16* __restrict__ Tb, float* __restrict__ tbl, int* __restrict__ pcnt,
    int* __restrict__ gbase, int* __restrict__ bsum, int* __restrict__ rowstart,
    u32* __restrict__ tmp, int* __restrict__ epk, u16* __restrict__ hW,
    float* __restrict__ out) {
  cg::grid_group grid = cg::this_grid();
  __shared__ int sm0[256];
  __shared__ int sm1[256];
  __shared__ int sm2[256];
  __shared__ int sm3[256];
  const int t = threadIdx.x;
  const int bid = blockIdx.x;

  // ==== Phase A: blocks 0..195 bucket histogram; 196..203 W/a prep ==========
  if (bid < NCHUNK) {
    const int c = bid;
    sm0[t] = 0;
    __syncthreads();
    const int base4 = c * CHUNK4;
    const int end4 = (base4 + CHUNK4 < NE4) ? base4 + CHUNK4 : NE4;
    for (int i = base4 + t; i < end4; i += 256) {
      int4 d4 = ((const int4*)dst)[i];
      atomicAdd(&sm0[d4.x >> 8], 1);
      atomicAdd(&sm0[d4.y >> 8], 1);
      atomicAdd(&sm0[d4.z >> 8], 1);
      atomicAdd(&sm0[d4.w >> 8], 1);
    }
    __syncthreads();
    if (t < NBUCK) pcnt[t * NCHUNK + c] = sm0[t];
  } else if (bid < NCHUNK + NREL) {
    const int r = bid - NCHUNK;
    for (int idx = t; idx < DIM * DIM; idx += 256) {
      int d = idx >> 6, k = idx & 63;
      WbT[((size_t)r * DIM + d) * DIM + k] = f2b(W[((size_t)r * DIM + k) * DIM + d]);
    }
    if (t < DIM) {
      int d = t;
      const float* Wr = W + (size_t)r * DIM * DIM + (size_t)d * DIM;
      const float* ar = a + (size_t)r * 2 * DIM + DIM;
      float acc = 0.f;
      #pragma unroll
      for (int e = 0; e < DIM; ++e) acc += Wr[e] * ar[e];
      Tb[(8 + r) * DIM + d] = f2b(acc);          // src-side: Wa2[r]
      Tb[r * DIM + d] = f2b(a[r * 2 * DIM + d]); // dst-side: a[r,:D]
    }
  }
  grid.sync();

  // ==== Phase B: blocks 0..781 h-cast + tbl MFMA; 782..932 scanA ============
  if (bid < NBLK) {
    const int wv = t >> 6;
    const int lane = t & 63;
    const int l15 = lane & 15;
    const int kg = lane >> 4;
    const int n = bid * 64 + wv * 16 + l15;
    const int nn = (n < N_NODES) ? n : N_NODES - 1;
    const float4* hr = (const float4*)(h + (size_t)nn * DIM);
    const float4 a0 = hr[kg * 2], a1 = hr[kg * 2 + 1];
    const float4 a2 = hr[8 + kg * 2], a3 = hr[8 + kg * 2 + 1];
    union { bf16x8 v; u32 w[4]; } b0, b1;
    b0.w[0] = (u32)f2b(a0.x) | ((u32)f2b(a0.y) << 16);
    b0.w[1] = (u32)f2b(a0.z) | ((u32)f2b(a0.w) << 16);
    b0.w[2] = (u32)f2b(a1.x) | ((u32)f2b(a1.y) << 16);
    b0.w[3] = (u32)f2b(a1.z) | ((u32)f2b(a1.w) << 16);
    b1.w[0] = (u32)f2b(a2.x) | ((u32)f2b(a2.y) << 16);
    b1.w[1] = (u32)f2b(a2.z) | ((u32)f2b(a2.w) << 16);
    b1.w[2] = (u32)f2b(a3.x) | ((u32)f2b(a3.y) << 16);
    b1.w[3] = (u32)f2b(a3.z) | ((u32)f2b(a3.w) << 16);
    const bool ok = (n < N_NODES);
    if (ok) {
      *(bf16x8*)(hb + (size_t)n * DIM + kg * 8) = b0.v;
      *(bf16x8*)(hb + (size_t)n * DIM + 32 + kg * 8) = b1.v;
    }
    const bf16x8* trow = (const bf16x8*)(Tb + (size_t)l15 * DIM);
    f32x4 acc = {0.f, 0.f, 0.f, 0.f};
    acc = __builtin_amdgcn_mfma_f32_16x16x32_bf16(trow[kg], b0.v, acc, 0, 0, 0);
    acc = __builtin_amdgcn_mfma_f32_16x16x32_bf16(trow[4 + kg], b1.v, acc, 0, 0, 0);
    if (ok) *(f32x4*)(tbl + (size_t)n * 16 + kg * 4) = acc;
  } else if (bid < NBLK + NSCAN) {
    const int sid = bid - NBLK;
    const int i = sid * 256 + t;
    const int v = (i < NP) ? pcnt[i] : 0;
    sm0[t] = v;
    __syncthreads();
    #pragma unroll
    for (int off = 1; off < 256; off <<= 1) {
      int tv = (t >= off) ? sm0[t - off] : 0;
      __syncthreads();
      sm0[t] += tv;
      __syncthreads();
    }
    if (i < NP) gbase[i] = sm0[t] - v;
    if (t == 255) bsum[sid] = sm0[255];
  }
  grid.sync();

  // ==== Phase C: blocks 0..195 partition pass 2; 196..977 hW MFMA GEMM ======
  if (bid < NCHUNK) {
    const int c = bid;
    {  // exclusive scan of bsum[NSCAN] -> sm0
      int v = (t < NSCAN) ? bsum[t] : 0;
      sm0[t] = v;
      __syncthreads();
      #pragma unroll
      for (int off = 1; off < 256; off <<= 1) {
        int tv = (t >= off) ? sm0[t - off] : 0;
        __syncthreads();
        sm0[t] += tv;
        __syncthreads();
      }
      int ex = sm0[t] - v;
      __syncthreads();
      sm0[t] = ex;
      __syncthreads();
    }
    if (t < NBUCK) {
      const int idx = t * NCHUNK + c;
      sm1[t] = gbase[idx] + sm0[idx >> 8];
    }
    __syncthreads();
    const int base4 = c * CHUNK4;
    const int end4 = (base4 + CHUNK4 < NE4) ? base4 + CHUNK4 : NE4;
    for (int i = base4 + t; i < end4; i += 256) {
      int4 s4 = ((const int4*)src)[i];
      int4 d4 = ((const int4*)dst)[i];
      int4 t4 = ((const int4*)et)[i];
      int p0 = atomicAdd(&sm1[d4.x >> 8], 1);
      int p1 = atomicAdd(&sm1[d4.y >> 8], 1);
      int p2 = atomicAdd(&sm1[d4.z >> 8], 1);
      int p3 = atomicAdd(&sm1[d4.w >> 8], 1);
      tmp[p0] = (u32)s4.x | ((u32)t4.x << 16) | ((u32)(d4.x & 255) << 24);
      tmp[p1] = (u32)s4.y | ((u32)t4.y << 16) | ((u32)(d4.y & 255) << 24);
      tmp[p2] = (u32)s4.z | ((u32)t4.z << 16) | ((u32)(d4.z & 255) << 24);
      tmp[p3] = (u32)s4.w | ((u32)t4.w << 16) | ((u32)(d4.w & 255) << 24);
    }
  } else {
    const int gb = bid - NCHUNK;
    const int wv = t >> 6;
    const int lane = t & 63;
    const int l15 = lane & 15;
    const int kg = lane >> 4;
    const int n = gb * 64 + wv * 16 + l15;
    const bf16x8* hrow = (const bf16x8*)(hb + (size_t)n * DIM);
    const bf16x8 b0 = hrow[kg];
    const bf16x8 b1 = hrow[4 + kg];
    const bool ok = (n < N_NODES);
    #pragma unroll
    for (int r = 0; r < NREL; ++r) {
      #pragma unroll
      for (int dt = 0; dt < 4; ++dt) {
        const int d = dt * 16 + l15;
        const bf16x8* wrow = (const bf16x8*)(WbT + ((size_t)r * DIM + d) * DIM);
        f32x4 acc = {0.f, 0.f, 0.f, 0.f};
        acc = __builtin_amdgcn_mfma_f32_16x16x32_bf16(wrow[kg], b0, acc, 0, 0, 0);
        acc = __builtin_amdgcn_mfma_f32_16x16x32_bf16(wrow[4 + kg], b1, acc, 0, 0, 0);
        if (ok) {
          uint2 s;
          s.x = (u32)f2b(acc[0]) | ((u32)f2b(acc[1]) << 16);
          s.y = (u32)f2b(acc[2]) | ((u32)f2b(acc[3]) << 16);
          *(uint2*)(hW + ((size_t)r * N_NODES + n) * DIM + dt * 16 + kg * 4) = s;
        }
      }
    }
  }
  grid.sync();

  // ==== Phase D: blocks 0..195 per-bucket LDS hist+scan -> rowstart, epk ====
  if (bid < NBUCK) {
    const int b = bid;
    {  // exclusive scan of bsum[NSCAN] -> sm0
      int v = (t < NSCAN) ? bsum[t] : 0;
      sm0[t] = v;
      __syncthreads();
      #pragma unroll
      for (int off = 1; off < 256; off <<= 1) {
        int tv = (t >= off) ? sm0[t - off] : 0;
        __syncthreads();
        sm0[t] += tv;
        __syncthreads();
      }
      int ex = sm0[t] - v;
      __syncthreads();
      sm0[t] = ex;
      __syncthreads();
    }
    const int i0 = b * NCHUNK;
    const int base = gbase[i0] + sm0[i0 >> 8];
    const int end = (b == NBUCK - 1)
                        ? N_EDGES
                        : (gbase[i0 + NCHUNK] + sm0[(i0 + NCHUNK) >> 8]);
    sm1[t] = 0;  // hist
    sm3[t] = 0;  // cur
    __syncthreads();
    for (int i = base + t; i < end; i += 256) atomicAdd(&sm1[tmp[i] >> 24], 1);
    __syncthreads();
    int v = sm1[t];
    sm2[t] = v;
    __syncthreads();
    #pragma unroll
    for (int off = 1; off < 256; off <<= 1) {
      int tv = (t >= off) ? sm2[t - off] : 0;
      __syncthreads();
      sm2[t] += tv;
      __syncthreads();
    }
    int myexcl = sm2[t] - v;
    __syncthreads();
    sm2[t] = myexcl;
    int n = b * 256 + t;
    if (n < N_NODES) rowstart[n] = base + myexcl;
    if (b == NBUCK - 1 && t == 0) rowstart[N_NODES] = N_EDGES;
    __syncthreads();
    for (int i = base + t; i < end; i += 256) {
      u32 p = tmp[i];
      int lo = p >> 24;
      int o = atomicAdd(&sm3[lo], 1);
      epk[base + sm2[lo] + o] = (int)(p & 0x7ffffu);  // (et<<16)|src
    }
  }
  grid.sync();

  // ==== Phase E: fused softmax+reduce (grid-stride over node groups) ========
  {
    const int wv = t >> 6;
    const int lane = t & 63;
    const int g = lane >> 3;   // edge slot 0..7
    const int l = lane & 7;    // 16B eighth of the 128B row
    for (int ng = bid; ng < NGRP; ng += NGRID) {
      const int node = ng * 4 + wv;
      const int s = rowstart[node];
      const int e = rowstart[node + 1];
      float acc[8];
      #pragma unroll
      for (int i = 0; i < 8; ++i) acc[i] = 0.f;
      float den = 0.f;
      for (int j = s; j < e; j += 16) {
        const int idx0 = j + g;
        const int idx1 = j + 8 + g;
        const bool v0 = idx0 < e;
        const bool v1 = idx1 < e;
        const int p0 = v0 ? epk[idx0] : 0;
        const int p1 = v1 ? epk[idx1] : 0;
        const int sv0 = p0 & 0xffff, rv0 = (p0 >> 16) & 7;
        const int sv1 = p1 & 0xffff, rv1 = (p1 >> 16) & 7;
        uint4 q0 = {0u, 0u, 0u, 0u}, q1 = {0u, 0u, 0u, 0u};
        if (v0) q0 = *(const uint4*)(hW + ((size_t)rv0 * N_NODES + sv0) * DIM + l * 8);
        if (v1) q1 = *(const uint4*)(hW + ((size_t)rv1 * N_NODES + sv1) * DIM + l * 8);
        float lg0 = tbl[(size_t)node * 16 + rv0] + tbl[(size_t)sv0 * 16 + 8 + rv0];
        float lg1 = tbl[(size_t)node * 16 + rv1] + tbl[(size_t)sv1 * 16 + 8 + rv1];
        lg0 = lg0 > 0.f ? lg0 : 0.2f * lg0;
        lg1 = lg1 > 0.f ? lg1 : 0.2f * lg1;
        const float w0 = v0 ? __expf(lg0) : 0.f;
        const float w1 = v1 ? __expf(lg1) : 0.f;
        den += w0 + w1;
        acc[0] += w0 * b2f((u16)(q0.x & 0xffff)) + w1 * b2f((u16)(q1.x & 0xffff));
        acc[1] += w0 * b2f((u16)(q0.x >> 16))    + w1 * b2f((u16)(q1.x >> 16));
        acc[2] += w0 * b2f((u16)(q0.y & 0xffff)) + w1 * b2f((u16)(q1.y & 0xffff));
        acc[3] += w0 * b2f((u16)(q0.y >> 16))    + w1 * b2f((u16)(q1.y >> 16));
        acc[4] += w0 * b2f((u16)(q0.z & 0xffff)) + w1 * b2f((u16)(q1.z & 0xffff));
        acc[5] += w0 * b2f((u16)(q0.z >> 16))    + w1 * b2f((u16)(q1.z >> 16));
        acc[6] += w0 * b2f((u16)(q0.w & 0xffff)) + w1 * b2f((u16)(q1.w & 0xffff));
        acc[7] += w0 * b2f((u16)(q0.w >> 16))    + w1 * b2f((u16)(q1.w >> 16));
      }
      #pragma unroll
      for (int m = 8; m <= 32; m <<= 1) {
        den += __shfl_xor(den, m, 64);
        #pragma unroll
        for (int i = 0; i < 8; ++i) acc[i] += __shfl_xor(acc[i], m, 64);
      }
      if (lane < 8) {
        const float inv = 1.f / (den + 1e-9f);
        const float4 hv0 = *(const float4*)(h + (size_t)node * DIM + l * 8);
        const float4 hv1 = *(const float4*)(h + (size_t)node * DIM + l * 8 + 4);
        const float4 dm0 = *(const float4*)(dmask + l * 8);
        const float4 dm1 = *(const float4*)(dmask + l * 8 + 4);
        float4 o0, o1;
        o0.x = hv0.x + acc[0] * inv * dm0.x;
        o0.y = hv0.y + acc[1] * inv * dm0.y;
        o0.z = hv0.z + acc[2] * inv * dm0.z;
        o0.w = hv0.w + acc[3] * inv * dm0.w;
        o1.x = hv1.x + acc[4] * inv * dm1.x;
        o1.y = hv1.y + acc[5] * inv * dm1.y;
        o1.z = hv1.z + acc[6] * inv * dm1.z;
        o1.w = hv1.w + acc[7] * inv * dm1.w;
        *(float4*)(out + (size_t)node * DIM + l * 8) = o0;
        *(float4*)(out + (size_t)node * DIM + l * 8 + 4) = o1;
      }
    }
  }
}

extern "C" void kernel_launch(void* const* d_in, const int* in_sizes, int n_in,
                              void* d_out, int out_size, void* d_ws, size_t ws_size,
                              hipStream_t stream) {
  const float* h = (const float*)d_in[0];
  const float* W = (const float*)d_in[1];
  const float* a = (const float*)d_in[2];
  const float* dmask = (const float*)d_in[3];
  const int* src = (const int*)d_in[4];
  const int* dst = (const int*)d_in[5];
  const int* et = (const int*)d_in[6];
  float* out = (float*)d_out;

  char* ws = (char*)d_ws;
  size_t off = 0;
  auto alloc = [&](size_t bytes) {
    void* p = ws + off;
    off += (bytes + 255) & ~(size_t)255;
    return p;
  };
  u16* hWbuf = (u16*)alloc((size_t)NREL * N_NODES * DIM * 2);  // 51.2 MB
  u16* hb = (u16*)alloc((size_t)NPAD * DIM * 2);               // 6.4 MB
  u16* WbT = (u16*)alloc((size_t)NREL * DIM * DIM * 2);
  u16* Tb = (u16*)alloc(16 * DIM * 2);
  float* tbl = (float*)alloc((size_t)N_NODES * 16 * 4);        // 3.2 MB
  int* rowstart = (int*)alloc((N_NODES + 1) * 4);
  int* pcnt = (int*)alloc(NP * 4);
  int* gbase = (int*)alloc(NP * 4);
  int* bsum = (int*)alloc(NSCAN * 4);
  u32* tmp = (u32*)alloc((size_t)N_EDGES * 4);                 // 3.2 MB
  int* epk = (int*)alloc((size_t)(N_EDGES + 64) * 4);
  (void)off; (void)ws_size;

  void* args[] = {&h,  &W,    &a,     &dmask, &src, &dst,      &et,  &hb,
                  &WbT, &Tb,  &tbl,   &pcnt,  &gbase, &bsum, &rowstart,
                  &tmp, &epk, &hWbuf, &out};
  hipLaunchCooperativeKernel((void*)k_mega, dim3(NGRID), dim3(256), args, 0,
                             stream);
}

// Round 17
// 96.596 us; speedup vs baseline: 6.0035x; 6.0035x over previous
//
#include <hip/hip_runtime.h>
#include <cstdint>
#include <cstddef>

#define N_NODES 50000
#define N_EDGES 800000
#define NE4 (N_EDGES / 4)        // 200000 int4 records
#define DIM 64
#define NREL 8
#define NBLK 782                 // ceil(N_NODES/64)
#define NPAD (NBLK * 64)         // 50048
#define NBUCK 196                // ceil(N_NODES/256): bucket = dst>>8
#define NCHUNK 196               // edge chunks of 4096
#define CHUNK4 1024              // int4 loads per chunk
#define NP (NBUCK * NCHUNK)      // 38416 count-matrix entries
#define NSCAN 151                // ceil(NP/256) scanA blocks

typedef unsigned short u16;
typedef unsigned int u32;
typedef float f32x4 __attribute__((ext_vector_type(4)));
typedef short bf16x8 __attribute__((ext_vector_type(8)));

__device__ __forceinline__ u16 f2b(float f) {
  union { float f; u32 u; } c; c.f = f;
  u32 u = c.u;
  return (u16)((u + 0x7fffu + ((u >> 16) & 1u)) >> 16);  // RNE
}
__device__ __forceinline__ float b2f(u16 v) {
  union { u32 u; float f; } c; c.u = ((u32)v) << 16;
  return c.f;
}

// ==== P1: blocks 0..195 = per-chunk bucket histogram; 196..203 = W/a prep ===
__global__ __launch_bounds__(256) void k_phase1(const int* __restrict__ dst,
                                                const float* __restrict__ W,
                                                const float* __restrict__ a,
                                                int* __restrict__ pcnt,
                                                u16* __restrict__ WbT,
                                                u16* __restrict__ Tb) {
  __shared__ int cnt[256];
  const int t = threadIdx.x;
  if (blockIdx.x < NCHUNK) {
    const int c = blockIdx.x;
    cnt[t] = 0;
    __syncthreads();
    const int base4 = c * CHUNK4;
    const int end4 = (base4 + CHUNK4 < NE4) ? base4 + CHUNK4 : NE4;
    for (int i = base4 + t; i < end4; i += 256) {
      int4 d4 = ((const int4*)dst)[i];
      atomicAdd(&cnt[d4.x >> 8], 1);
      atomicAdd(&cnt[d4.y >> 8], 1);
      atomicAdd(&cnt[d4.z >> 8], 1);
      atomicAdd(&cnt[d4.w >> 8], 1);
    }
    __syncthreads();
    if (t < NBUCK) pcnt[t * NCHUNK + c] = cnt[t];
  } else {
    const int r = blockIdx.x - NCHUNK;
    for (int idx = t; idx < DIM * DIM; idx += 256) {
      int d = idx >> 6, k = idx & 63;
      WbT[((size_t)r * DIM + d) * DIM + k] = f2b(W[((size_t)r * DIM + k) * DIM + d]);
    }
    if (t < DIM) {
      int d = t;
      const float* Wr = W + (size_t)r * DIM * DIM + (size_t)d * DIM;
      const float* ar = a + (size_t)r * 2 * DIM + DIM;
      float acc = 0.f;
      #pragma unroll
      for (int e = 0; e < DIM; ++e) acc += Wr[e] * ar[e];
      Tb[(8 + r) * DIM + d] = f2b(acc);          // src-side: Wa2[r]
      Tb[r * DIM + d] = f2b(a[r * 2 * DIM + d]); // dst-side: a[r,:D]
    }
  }
}

// ==== P2: blocks 0..781 = fused h-cast + logit-table MFMA;
//          blocks 782..932 = scanA (block-local scan of pcnt -> gbase, bsum) =
__global__ __launch_bounds__(256) void k_phase2(const float* __restrict__ h,
                                                const u16* __restrict__ Tb,
                                                const int* __restrict__ pcnt,
                                                u16* __restrict__ hb,
                                                float* __restrict__ tbl,
                                                int* __restrict__ gbase,
                                                int* __restrict__ bsum) {
  __shared__ int lds[256];
  const int t = threadIdx.x;
  if (blockIdx.x < NBLK) {
    const int wv = t >> 6;
    const int lane = t & 63;
    const int l15 = lane & 15;
    const int kg = lane >> 4;
    const int n = blockIdx.x * 64 + wv * 16 + l15;
    const int nn = (n < N_NODES) ? n : N_NODES - 1;  // clamp reads; mask stores
    const float4* hr = (const float4*)(h + (size_t)nn * DIM);
    const float4 a0 = hr[kg * 2], a1 = hr[kg * 2 + 1];
    const float4 a2 = hr[8 + kg * 2], a3 = hr[8 + kg * 2 + 1];
    union { bf16x8 v; u32 w[4]; } b0, b1;
    b0.w[0] = (u32)f2b(a0.x) | ((u32)f2b(a0.y) << 16);
    b0.w[1] = (u32)f2b(a0.z) | ((u32)f2b(a0.w) << 16);
    b0.w[2] = (u32)f2b(a1.x) | ((u32)f2b(a1.y) << 16);
    b0.w[3] = (u32)f2b(a1.z) | ((u32)f2b(a1.w) << 16);
    b1.w[0] = (u32)f2b(a2.x) | ((u32)f2b(a2.y) << 16);
    b1.w[1] = (u32)f2b(a2.z) | ((u32)f2b(a2.w) << 16);
    b1.w[2] = (u32)f2b(a3.x) | ((u32)f2b(a3.y) << 16);
    b1.w[3] = (u32)f2b(a3.z) | ((u32)f2b(a3.w) << 16);
    const bool ok = (n < N_NODES);
    if (ok) {
      *(bf16x8*)(hb + (size_t)n * DIM + kg * 8) = b0.v;
      *(bf16x8*)(hb + (size_t)n * DIM + 32 + kg * 8) = b1.v;
    }
    const bf16x8* trow = (const bf16x8*)(Tb + (size_t)l15 * DIM);
    f32x4 acc = {0.f, 0.f, 0.f, 0.f};
    acc = __builtin_amdgcn_mfma_f32_16x16x32_bf16(trow[kg], b0.v, acc, 0, 0, 0);
    acc = __builtin_amdgcn_mfma_f32_16x16x32_bf16(trow[4 + kg], b1.v, acc, 0, 0, 0);
    if (ok) *(f32x4*)(tbl + (size_t)n * 16 + kg * 4) = acc;
  } else {
    const int sid = blockIdx.x - NBLK;      // 0..150
    const int i = sid * 256 + t;
    const int v = (i < NP) ? pcnt[i] : 0;
    lds[t] = v;
    __syncthreads();
    #pragma unroll
    for (int off = 1; off < 256; off <<= 1) {
      int tv = (t >= off) ? lds[t - off] : 0;
      __syncthreads();
      lds[t] += tv;
      __syncthreads();
    }
    if (i < NP) gbase[i] = lds[t] - v;      // block-local exclusive
    if (t == 255) bsum[sid] = lds[255];
  }
}

// ==== P3: blocks 0..195 = partition pass 2 (in-block boff scan);
//          blocks 196..977 = hW MFMA GEMM ====================================
// pack: bits[15:0]=src, [18:16]=et, [31:24]=dst&255
__global__ __launch_bounds__(256) void k_phase3(const int* __restrict__ src,
                                                const int* __restrict__ dst,
                                                const int* __restrict__ et,
                                                const int* __restrict__ gbase,
                                                const int* __restrict__ bsum,
                                                u32* __restrict__ tmp,
                                                const u16* __restrict__ hb,
                                                const u16* __restrict__ WbT,
                                                u16* __restrict__ hW) {
  __shared__ int boffs[256];
  __shared__ int cur[256];
  const int t = threadIdx.x;
  if (blockIdx.x < NCHUNK) {
    const int c = blockIdx.x;
    {  // exclusive scan of bsum[NSCAN]
      int v = (t < NSCAN) ? bsum[t] : 0;
      boffs[t] = v;
      __syncthreads();
      #pragma unroll
      for (int off = 1; off < 256; off <<= 1) {
        int tv = (t >= off) ? boffs[t - off] : 0;
        __syncthreads();
        boffs[t] += tv;
        __syncthreads();
      }
      int ex = boffs[t] - v;
      __syncthreads();
      boffs[t] = ex;
      __syncthreads();
    }
    if (t < NBUCK) {
      const int idx = t * NCHUNK + c;
      cur[t] = gbase[idx] + boffs[idx >> 8];
    }
    __syncthreads();
    const int base4 = c * CHUNK4;
    const int end4 = (base4 + CHUNK4 < NE4) ? base4 + CHUNK4 : NE4;
    for (int i = base4 + t; i < end4; i += 256) {
      int4 s4 = ((const int4*)src)[i];
      int4 d4 = ((const int4*)dst)[i];
      int4 t4 = ((const int4*)et)[i];
      int p0 = atomicAdd(&cur[d4.x >> 8], 1);
      int p1 = atomicAdd(&cur[d4.y >> 8], 1);
      int p2 = atomicAdd(&cur[d4.z >> 8], 1);
      int p3 = atomicAdd(&cur[d4.w >> 8], 1);
      tmp[p0] = (u32)s4.x | ((u32)t4.x << 16) | ((u32)(d4.x & 255) << 24);
      tmp[p1] = (u32)s4.y | ((u32)t4.y << 16) | ((u32)(d4.y & 255) << 24);
      tmp[p2] = (u32)s4.z | ((u32)t4.z << 16) | ((u32)(d4.z & 255) << 24);
      tmp[p3] = (u32)s4.w | ((u32)t4.w << 16) | ((u32)(d4.w & 255) << 24);
    }
  } else {
    const int bid = blockIdx.x - NCHUNK;
    const int wv = t >> 6;
    const int lane = t & 63;
    const int l15 = lane & 15;
    const int kg = lane >> 4;
    const int n = bid * 64 + wv * 16 + l15;
    const bf16x8* hrow = (const bf16x8*)(hb + (size_t)n * DIM);
    const bf16x8 b0 = hrow[kg];
    const bf16x8 b1 = hrow[4 + kg];
    const bool ok = (n < N_NODES);
    #pragma unroll
    for (int r = 0; r < NREL; ++r) {
      #pragma unroll
      for (int dt = 0; dt < 4; ++dt) {
        const int d = dt * 16 + l15;
        const bf16x8* wrow = (const bf16x8*)(WbT + ((size_t)r * DIM + d) * DIM);
        f32x4 acc = {0.f, 0.f, 0.f, 0.f};
        acc = __builtin_amdgcn_mfma_f32_16x16x32_bf16(wrow[kg], b0, acc, 0, 0, 0);
        acc = __builtin_amdgcn_mfma_f32_16x16x32_bf16(wrow[4 + kg], b1, acc, 0, 0, 0);
        if (ok) {
          uint2 s;
          s.x = (u32)f2b(acc[0]) | ((u32)f2b(acc[1]) << 16);
          s.y = (u32)f2b(acc[2]) | ((u32)f2b(acc[3]) << 16);
          *(uint2*)(hW + ((size_t)r * N_NODES + n) * DIM + dt * 16 + kg * 4) = s;
        }
      }
    }
  }
}

// ==== P4: per bucket LDS hist+scan -> rowstart + node-grouped epk ===========
__global__ __launch_bounds__(256) void k_local(const u32* __restrict__ tmp,
                                               const int* __restrict__ gbase,
                                               const int* __restrict__ bsum,
                                               int* __restrict__ rowstart,
                                               int* __restrict__ epk) {
  __shared__ int boffs[256];
  __shared__ int hist[256];
  __shared__ int excl[256];
  __shared__ int cur[256];
  const int b = blockIdx.x;
  const int t = threadIdx.x;
  {  // exclusive scan of bsum[NSCAN]
    int v = (t < NSCAN) ? bsum[t] : 0;
    boffs[t] = v;
    __syncthreads();
    #pragma unroll
    for (int off = 1; off < 256; off <<= 1) {
      int tv = (t >= off) ? boffs[t - off] : 0;
      __syncthreads();
      boffs[t] += tv;
      __syncthreads();
    }
    int ex = boffs[t] - v;
    __syncthreads();
    boffs[t] = ex;
    __syncthreads();
  }
  const int i0 = b * NCHUNK;
  const int base = gbase[i0] + boffs[i0 >> 8];
  const int end = (b == NBUCK - 1)
                      ? N_EDGES
                      : (gbase[i0 + NCHUNK] + boffs[(i0 + NCHUNK) >> 8]);
  hist[t] = 0;
  cur[t] = 0;
  __syncthreads();
  for (int i = base + t; i < end; i += 256) atomicAdd(&hist[tmp[i] >> 24], 1);
  __syncthreads();
  int v = hist[t];
  excl[t] = v;
  __syncthreads();
  #pragma unroll
  for (int off = 1; off < 256; off <<= 1) {
    int tv = (t >= off) ? excl[t - off] : 0;
    __syncthreads();
    excl[t] += tv;
    __syncthreads();
  }
  int myexcl = excl[t] - v;
  excl[t] = myexcl;
  int n = b * 256 + t;
  if (n < N_NODES) rowstart[n] = base + myexcl;
  if (b == NBUCK - 1 && t == 0) rowstart[N_NODES] = N_EDGES;
  __syncthreads();
  for (int i = base + t; i < end; i += 256) {
    u32 p = tmp[i];
    int lo = p >> 24;
    int o = atomicAdd(&cur[lo], 1);
    epk[base + excl[lo] + o] = (int)(p & 0x7ffffu);  // (et<<16)|src
  }
}

// ==== P5: fused softmax+reduce: wave/node, 8 slots x 8 lanes, unroll 4 ======
// Four independent 8-edge groups per iteration -> 32 hW rows in flight/wave;
// ~97% of nodes (deg<=32) finish in one iteration.
__global__ void k_fused(const float* __restrict__ h, const u16* __restrict__ hW,
                        const float* __restrict__ tbl,
                        const int* __restrict__ rowstart, const int* __restrict__ epk,
                        const float* __restrict__ dmask, float* __restrict__ out) {
  const int node = blockIdx.x * 4 + (threadIdx.x >> 6);
  const int lane = threadIdx.x & 63;
  const int g = lane >> 3;   // edge slot 0..7
  const int l = lane & 7;    // 16B eighth of the 128B row
  const int s = rowstart[node];
  const int e = rowstart[node + 1];
  float acc[8];
  #pragma unroll
  for (int i = 0; i < 8; ++i) acc[i] = 0.f;
  float den = 0.f;
  for (int j = s; j < e; j += 32) {
    const int idx0 = j + g;
    const int idx1 = j + 8 + g;
    const int idx2 = j + 16 + g;
    const int idx3 = j + 24 + g;
    const bool v0 = idx0 < e;
    const bool v1 = idx1 < e;
    const bool v2 = idx2 < e;
    const bool v3 = idx3 < e;
    const int p0 = v0 ? epk[idx0] : 0;
    const int p1 = v1 ? epk[idx1] : 0;
    const int p2 = v2 ? epk[idx2] : 0;
    const int p3 = v3 ? epk[idx3] : 0;
    const int sv0 = p0 & 0xffff, rv0 = (p0 >> 16) & 7;
    const int sv1 = p1 & 0xffff, rv1 = (p1 >> 16) & 7;
    const int sv2 = p2 & 0xffff, rv2 = (p2 >> 16) & 7;
    const int sv3 = p3 & 0xffff, rv3 = (p3 >> 16) & 7;
    uint4 q0 = {0u, 0u, 0u, 0u}, q1 = {0u, 0u, 0u, 0u};
    uint4 q2 = {0u, 0u, 0u, 0u}, q3 = {0u, 0u, 0u, 0u};
    if (v0) q0 = *(const uint4*)(hW + ((size_t)rv0 * N_NODES + sv0) * DIM + l * 8);
    if (v1) q1 = *(const uint4*)(hW + ((size_t)rv1 * N_NODES + sv1) * DIM + l * 8);
    if (v2) q2 = *(const uint4*)(hW + ((size_t)rv2 * N_NODES + sv2) * DIM + l * 8);
    if (v3) q3 = *(const uint4*)(hW + ((size_t)rv3 * N_NODES + sv3) * DIM + l * 8);
    float lg0 = tbl[(size_t)node * 16 + rv0] + tbl[(size_t)sv0 * 16 + 8 + rv0];
    float lg1 = tbl[(size_t)node * 16 + rv1] + tbl[(size_t)sv1 * 16 + 8 + rv1];
    float lg2 = tbl[(size_t)node * 16 + rv2] + tbl[(size_t)sv2 * 16 + 8 + rv2];
    float lg3 = tbl[(size_t)node * 16 + rv3] + tbl[(size_t)sv3 * 16 + 8 + rv3];
    lg0 = lg0 > 0.f ? lg0 : 0.2f * lg0;
    lg1 = lg1 > 0.f ? lg1 : 0.2f * lg1;
    lg2 = lg2 > 0.f ? lg2 : 0.2f * lg2;
    lg3 = lg3 > 0.f ? lg3 : 0.2f * lg3;
    const float w0 = v0 ? __expf(lg0) : 0.f;
    const float w1 = v1 ? __expf(lg1) : 0.f;
    const float w2 = v2 ? __expf(lg2) : 0.f;
    const float w3 = v3 ? __expf(lg3) : 0.f;
    den += (w0 + w1) + (w2 + w3);
    acc[0] += w0 * b2f((u16)(q0.x & 0xffff)) + w1 * b2f((u16)(q1.x & 0xffff))
            + w2 * b2f((u16)(q2.x & 0xffff)) + w3 * b2f((u16)(q3.x & 0xffff));
    acc[1] += w0 * b2f((u16)(q0.x >> 16))    + w1 * b2f((u16)(q1.x >> 16))
            + w2 * b2f((u16)(q2.x >> 16))    + w3 * b2f((u16)(q3.x >> 16));
    acc[2] += w0 * b2f((u16)(q0.y & 0xffff)) + w1 * b2f((u16)(q1.y & 0xffff))
            + w2 * b2f((u16)(q2.y & 0xffff)) + w3 * b2f((u16)(q3.y & 0xffff));
    acc[3] += w0 * b2f((u16)(q0.y >> 16))    + w1 * b2f((u16)(q1.y >> 16))
            + w2 * b2f((u16)(q2.y >> 16))    + w3 * b2f((u16)(q3.y >> 16));
    acc[4] += w0 * b2f((u16)(q0.z & 0xffff)) + w1 * b2f((u16)(q1.z & 0xffff))
            + w2 * b2f((u16)(q2.z & 0xffff)) + w3 * b2f((u16)(q3.z & 0xffff));
    acc[5] += w0 * b2f((u16)(q0.z >> 16))    + w1 * b2f((u16)(q1.z >> 16))
            + w2 * b2f((u16)(q2.z >> 16))    + w3 * b2f((u16)(q3.z >> 16));
    acc[6] += w0 * b2f((u16)(q0.w & 0xffff)) + w1 * b2f((u16)(q1.w & 0xffff))
            + w2 * b2f((u16)(q2.w & 0xffff)) + w3 * b2f((u16)(q3.w & 0xffff));
    acc[7] += w0 * b2f((u16)(q0.w >> 16))    + w1 * b2f((u16)(q1.w >> 16))
            + w2 * b2f((u16)(q2.w >> 16))    + w3 * b2f((u16)(q3.w >> 16));
  }
  // combine the 8 edge slots (strides 8, 16, 32)
  #pragma unroll
  for (int m = 8; m <= 32; m <<= 1) {
    den += __shfl_xor(den, m, 64);
    #pragma unroll
    for (int i = 0; i < 8; ++i) acc[i] += __shfl_xor(acc[i], m, 64);
  }
  if (lane < 8) {
    const float inv = 1.f / (den + 1e-9f);
    const float4 hv0 = *(const float4*)(h + (size_t)node * DIM + l * 8);
    const float4 hv1 = *(const float4*)(h + (size_t)node * DIM + l * 8 + 4);
    const float4 dm0 = *(const float4*)(dmask + l * 8);
    const float4 dm1 = *(const float4*)(dmask + l * 8 + 4);
    float4 o0, o1;
    o0.x = hv0.x + acc[0] * inv * dm0.x;
    o0.y = hv0.y + acc[1] * inv * dm0.y;
    o0.z = hv0.z + acc[2] * inv * dm0.z;
    o0.w = hv0.w + acc[3] * inv * dm0.w;
    o1.x = hv1.x + acc[4] * inv * dm1.x;
    o1.y = hv1.y + acc[5] * inv * dm1.y;
    o1.z = hv1.z + acc[6] * inv * dm1.z;
    o1.w = hv1.w + acc[7] * inv * dm1.w;
    *(float4*)(out + (size_t)node * DIM + l * 8) = o0;
    *(float4*)(out + (size_t)node * DIM + l * 8 + 4) = o1;
  }
}

extern "C" void kernel_launch(void* const* d_in, const int* in_sizes, int n_in,
                              void* d_out, int out_size, void* d_ws, size_t ws_size,
                              hipStream_t stream) {
  const float* h = (const float*)d_in[0];
  const float* W = (const float*)d_in[1];
  const float* a = (const float*)d_in[2];
  const float* dmask = (const float*)d_in[3];
  const int* src = (const int*)d_in[4];
  const int* dst = (const int*)d_in[5];
  const int* et = (const int*)d_in[6];
  float* out = (float*)d_out;

  char* ws = (char*)d_ws;
  size_t off = 0;
  auto alloc = [&](size_t bytes) {
    void* p = ws + off;
    off += (bytes + 255) & ~(size_t)255;
    return p;
  };
  u16* hWbuf = (u16*)alloc((size_t)NREL * N_NODES * DIM * 2);  // 51.2 MB
  u16* hb = (u16*)alloc((size_t)NPAD * DIM * 2);               // 6.4 MB
  u16* WbT = (u16*)alloc((size_t)NREL * DIM * DIM * 2);
  u16* Tb = (u16*)alloc(16 * DIM * 2);
  float* tbl = (float*)alloc((size_t)N_NODES * 16 * 4);        // 3.2 MB
  int* rowstart = (int*)alloc((N_NODES + 1) * 4);
  int* pcnt = (int*)alloc(NP * 4);
  int* gbase = (int*)alloc(NP * 4);
  int* bsum = (int*)alloc(NSCAN * 4);
  u32* tmp = (u32*)alloc((size_t)N_EDGES * 4);                 // 3.2 MB
  int* epk = (int*)alloc((size_t)(N_EDGES + 64) * 4);
  (void)off; (void)ws_size;

  k_phase1<<<NCHUNK + NREL, 256, 0, stream>>>(dst, W, a, pcnt, WbT, Tb);
  k_phase2<<<NBLK + NSCAN, 256, 0, stream>>>(h, Tb, pcnt, hb, tbl, gbase, bsum);
  k_phase3<<<NCHUNK + NBLK, 256, 0, stream>>>(src, dst, et, gbase, bsum, tmp, hb,
                                              WbT, hWbuf);
  k_local<<<NBUCK, 256, 0, stream>>>(tmp, gbase, bsum, rowstart, epk);
  k_fused<<<N_NODES / 4, 256, 0, stream>>>(h, hWbuf, tbl, rowstart, epk, dmask, out);
}